// Round 10
// baseline (1909.374 us; speedup 1.0000x reference)
//
#include <hip/hip_runtime.h>
#include <math.h>

// Spectral regularization: 1e-4 * (sigma_max(w1) + sigma_max(w2) + sigma_max(w3))
// Lanczos (K=24, no reorth) on B = F^T F, F = fp8-e4m3(A) (50 MB, L3-resident).
// Per step: ONE kernel. Each block: phase1 row dots (w = F u, alpha atomic),
// phase2 L2-hot re-read -> column partials (plain stores). Epilogue: last 16
// arriving blocks per matrix (device-scope counter + fences) collaboratively
// reduce the partials and do the alpha/beta update in 1/16-column slices.
// Top Ritz vector v* measured on fp32 A: sigma = ||A v*|| / ||v*||.
//
// Shapes (row-major): w1 4096x4096, w2 8192x2048, w3 2048x8192 (each 16777216)

#define K_STEPS 24
#define VCAP 8192
#define MELEMS 16777216
#define NCHUNK 256
#define NFIN 16

// fp8-path vec layout (floats)
#define UOFF   0                                  // u_j (unnormalized residual), 3*VCAP
#define V0OFF  (3 * VCAP)                         // v_{j-1} normalized
#define WOFF   (6 * VCAP)                         // w; later v*
#define P8OFF  (9 * VCAP)                         // partials (R8 layout, 14 MB)
#define P8TOT  3670016
#define BASOFF (P8OFF + P8TOT)                    // basis, 3*K*VCAP
#define AL8OFF (BASOFF + 3 * K_STEPS * VCAP)      // ALPHA [3][K]
#define B28OFF (AL8OFF + 3 * K_STEPS)             // B2 [3][K+1]
#define NS2OFF (B28OFF + 3 * (K_STEPS + 1))       // ||v*||^2 [3]
#define RQ2OFF (NS2OFF + 3)                       // ||A v*||^2 [3]
#define CNTOFF (RQ2OFF + 3)                       // CNT [3][K] ints
#define VEC8_FLOATS (CNTOFF + 3 * K_STEPS)

// fp32 fallback layout
#define FB_AOFF (12 * VCAP)

typedef unsigned int u32;
typedef float f32x2 __attribute__((ext_vector_type(2)));

__device__ __forceinline__ int matN(int m) { return m == 0 ? 4096 : (m == 1 ? 2048 : 8192); }
__device__ __forceinline__ int pbase(int m) { return m == 0 ? 0 : (m == 1 ? 1048576 : 1572864); }

__device__ __forceinline__ f32x2 up8(u32 w, bool hi) {
    return hi ? __builtin_amdgcn_cvt_pk_f32_fp8(w, true)
              : __builtin_amdgcn_cvt_pk_f32_fp8(w, false);
}

__device__ float blockReduce(float v) {
    __shared__ float sh[16];
    int lane = threadIdx.x & 63, wid = threadIdx.x >> 6;
#pragma unroll
    for (int off = 32; off; off >>= 1) v += __shfl_down(v, off, 64);
    if (lane == 0) sh[wid] = v;
    __syncthreads();
    if (wid == 0) {
        int nw = (blockDim.x + 63) >> 6;
        float x = (lane < nw) ? sh[lane] : 0.0f;
#pragma unroll
        for (int off = 8; off; off >>= 1) x += __shfl_down(x, off, 64);
        if (lane == 0) sh[0] = x;
    }
    __syncthreads();
    float r = sh[0];
    __syncthreads();
    return r;
}

// ======================= fp8 path =======================

// convert (blocks 0..3071) + init (tail blocks; zeroes counters each launch)
__global__ __launch_bounds__(256) void k_conv_init(const float* __restrict__ A0,
                                                   const float* __restrict__ A1,
                                                   const float* __restrict__ A2,
                                                   u32* __restrict__ F,
                                                   float* __restrict__ vec) {
    int bid = blockIdx.x, tid = threadIdx.x;
    if (bid < 3072) {
        const int per16 = MELEMS >> 4;
        const int nvec16 = 3 * per16;
        for (int i = bid * 256 + tid; i < nvec16; i += 3072 * 256) {
            int mat = i >> 20;
            int iv = i & (per16 - 1);
            const float4* Af = (const float4*)(mat == 0 ? A0 : (mat == 1 ? A1 : A2));
            float4 a = Af[4 * iv + 0], b = Af[4 * iv + 1];
            float4 c = Af[4 * iv + 2], d = Af[4 * iv + 3];
            uint4 o;
            o.x = __builtin_amdgcn_cvt_pk_fp8_f32(a.x, a.y, 0u, false);
            o.x = __builtin_amdgcn_cvt_pk_fp8_f32(a.z, a.w, o.x, true);
            o.y = __builtin_amdgcn_cvt_pk_fp8_f32(b.x, b.y, 0u, false);
            o.y = __builtin_amdgcn_cvt_pk_fp8_f32(b.z, b.w, o.y, true);
            o.z = __builtin_amdgcn_cvt_pk_fp8_f32(c.x, c.y, 0u, false);
            o.z = __builtin_amdgcn_cvt_pk_fp8_f32(c.z, c.w, o.z, true);
            o.w = __builtin_amdgcn_cvt_pk_fp8_f32(d.x, d.y, 0u, false);
            o.w = __builtin_amdgcn_cvt_pk_fp8_f32(d.z, d.w, o.w, true);
            ((uint4*)F)[i] = o;
        }
    } else if (bid < 3075) {
        int mat = bid - 3072, n = matN(mat);
        float acc = 0.0f;
        for (int i = tid; i < VCAP; i += 256) {
            float val = 0.0f;
            if (i < n) {
                unsigned h = (unsigned)(i * 2654435761u) ^ (0x9E3779B9u * (unsigned)(mat + 1));
                h ^= h >> 16; h *= 0x85EBCA6Bu; h ^= h >> 13; h *= 0xC2B2AE35u; h ^= h >> 16;
                val = ((h >> 8) * (1.0f / 16777216.0f)) - 0.5f;
                acc += val * val;
            }
            vec[UOFF + mat * VCAP + i] = val;
            vec[V0OFF + mat * VCAP + i] = 0.0f;
        }
        float nrm2 = blockReduce(acc);
        if (tid == 0) vec[B28OFF + mat * (K_STEPS + 1)] = nrm2;
    } else {
        for (int i = tid; i < 3 * K_STEPS; i += 256) vec[AL8OFF + i] = 0.0f;
        for (int i = tid; i < 3 * (K_STEPS + 1); i += 256)
            if (i % (K_STEPS + 1)) vec[B28OFF + i] = 0.0f;
        if (tid < 3) { vec[NS2OFF + tid] = 0.0f; vec[RQ2OFF + tid] = 0.0f; }
        int* cnt = (int*)(vec + CNTOFF);
        for (int i = tid; i < 3 * K_STEPS; i += 256) cnt[i] = 0;
    }
}

// ---- fused step kernel (R8 structure + finisher epilogue) ----
// block = R rows x N cols (64 KB fp8), 256 chunks per matrix.
template <int N, int R>
__device__ void fusedAT_body(const u32* __restrict__ Fm, float* __restrict__ vec,
                             int mat, int chunk, int j,
                             float* __restrict__ Pm, float* wsh, float* shA,
                             int* shSl) {
    constexpr int RPW = R / 4;
    constexpr int NU4 = N >> 4;
    constexpr int KK  = N >> 11;
    const int tid = threadIdx.x, wv = tid >> 6, lane = tid & 63;
    const int row0 = chunk * R;

    // ---- phase 1: row dots ----
    float inv = rsqrtf(vec[B28OFF + mat * (K_STEPS + 1) + j]);
    const float4* vp = (const float4*)(vec + UOFF + mat * VCAP);
    float aacc = 0.0f;
#pragma unroll
    for (int rr = 0; rr < RPW; ++rr) {
        int rl = wv * RPW + rr;
        const uint4* rp = (const uint4*)((const char*)Fm + (size_t)(row0 + rl) * N);
        float s = 0.0f;
#pragma unroll
        for (int c = lane; c < NU4; c += 64) {
            uint4 a = rp[c];
            float4 u0 = vp[4 * c + 0], u1 = vp[4 * c + 1];
            float4 u2 = vp[4 * c + 2], u3 = vp[4 * c + 3];
            f32x2 f0 = up8(a.x, false), f1 = up8(a.x, true);
            f32x2 f2 = up8(a.y, false), f3 = up8(a.y, true);
            f32x2 f4 = up8(a.z, false), f5 = up8(a.z, true);
            f32x2 f6 = up8(a.w, false), f7 = up8(a.w, true);
            s += f0[0] * u0.x + f0[1] * u0.y + f1[0] * u0.z + f1[1] * u0.w
               + f2[0] * u1.x + f2[1] * u1.y + f3[0] * u1.z + f3[1] * u1.w
               + f4[0] * u2.x + f4[1] * u2.y + f5[0] * u2.z + f5[1] * u2.w
               + f6[0] * u3.x + f6[1] * u3.y + f7[0] * u3.z + f7[1] * u3.w;
        }
#pragma unroll
        for (int off = 32; off; off >>= 1) s += __shfl_down(s, off, 64);
        if (lane == 0) { wsh[rl] = s * inv; aacc += s * s; }
    }
    if (lane == 0) shA[wv] = aacc;
    __syncthreads();
    if (tid == 0)
        atomicAdd(&vec[AL8OFF + mat * K_STEPS + j],
                  (shA[0] + shA[1] + shA[2] + shA[3]) * inv * inv);

    // ---- phase 2: column partials (tile L2-hot) ----
#pragma unroll
    for (int kk = 0; kk < KK; ++kk) {
        int col = (tid + (kk << 8)) << 3;
        const char* bb = (const char*)Fm + (size_t)row0 * N + col;
        float a0 = 0, a1 = 0, a2 = 0, a3 = 0, a4 = 0, a5 = 0, a6 = 0, a7 = 0;
#pragma unroll 8
        for (int r = 0; r < R; ++r) {
            uint2 a = *(const uint2*)(bb + (size_t)r * N);
            f32x2 f0 = up8(a.x, false), f1 = up8(a.x, true);
            f32x2 f2 = up8(a.y, false), f3 = up8(a.y, true);
            float w = wsh[r];
            a0 += f0[0] * w; a1 += f0[1] * w; a2 += f1[0] * w; a3 += f1[1] * w;
            a4 += f2[0] * w; a5 += f2[1] * w; a6 += f3[0] * w; a7 += f3[1] * w;
        }
        float* Pp = Pm + (size_t)chunk * N + col;
        float4 lo = {a0, a1, a2, a3}, hi = {a4, a5, a6, a7};
        ((float4*)Pp)[0] = lo;
        ((float4*)Pp)[1] = hi;
    }

    // ---- epilogue: last NFIN arrivals reduce+update a 1/NFIN column slice ----
    __syncthreads();                // drains this block's stores (vmcnt 0)
    int* cnt = (int*)(vec + CNTOFF) + mat * K_STEPS + j;
    if (tid == 0) {
        __threadfence();            // release: write back to device-coherent point
        int old = atomicAdd(cnt, 1);
        int sl = old - (NCHUNK - NFIN);
        if (sl >= 0) {
            while (__hip_atomic_load(cnt, __ATOMIC_RELAXED, __HIP_MEMORY_SCOPE_AGENT) < NCHUNK)
                __builtin_amdgcn_s_sleep(2);
            __threadfence();        // acquire: invalidate local caches
        }
        *shSl = sl;
    }
    __syncthreads();
    int sl = *shSl;
    if (sl < 0) return;

    // stepR work on columns [sl*sliceN, (sl+1)*sliceN)
    constexpr int sliceN = N / NFIN;
    float b2p = vec[B28OFF + mat * (K_STEPS + 1) + j];
    float bp = sqrtf(b2p);
    float invb = 1.0f / bp;
    float alpha = vec[AL8OFF + mat * K_STEPS + j];
    float rr2 = 0.0f;
    for (int c = sl * sliceN + tid; c < (sl + 1) * sliceN; c += 256) {
        float z = 0.0f;
#pragma unroll 8
        for (int rc = 0; rc < NCHUNK; ++rc) z += Pm[(size_t)rc * N + c];
        int g = mat * VCAP + c;
        float v1 = vec[UOFF + g] * invb;
        float r = z - alpha * v1 - bp * vec[V0OFF + g];
        vec[V0OFF + g] = v1;
        vec[UOFF + g] = r;
        vec[BASOFF + (mat * K_STEPS + j) * VCAP + c] = v1;
        rr2 += r * r;
    }
    float t = blockReduce(rr2);
    if (tid == 0) atomicAdd(&vec[B28OFF + mat * (K_STEPS + 1) + j + 1], t);
}

__global__ __launch_bounds__(256) void k_fusedAT(const u32* __restrict__ F,
                                                 float* __restrict__ vec, int j) {
    __shared__ float wsh[32];
    __shared__ float shA[4];
    __shared__ int shSl;
    int bid = blockIdx.x;
    if (bid < 256) {
        fusedAT_body<4096, 16>((const u32*)((const char*)F + (size_t)0 * MELEMS),
                               vec, 0, bid, j, vec + P8OFF + pbase(0), wsh, shA, &shSl);
    } else if (bid < 512) {
        fusedAT_body<2048, 32>((const u32*)((const char*)F + (size_t)1 * MELEMS),
                               vec, 1, bid - 256, j, vec + P8OFF + pbase(1), wsh, shA, &shSl);
    } else {
        fusedAT_body<8192, 8>((const u32*)((const char*)F + (size_t)2 * MELEMS),
                              vec, 2, bid - 512, j, vec + P8OFF + pbase(2), wsh, shA, &shSl);
    }
}

// Sturm lambda_max + 3 inverse iterations -> y ; v* = Basis^T y (quarter per block).
__global__ __launch_bounds__(256) void k_final3(float* __restrict__ vec) {
    int bid = blockIdx.x;
    int mat = bid >> 2, q = bid & 3, tid = threadIdx.x, lane = tid & 63, wv = tid >> 6;
    int n = matN(mat);
    __shared__ double sa[K_STEPS], sb[K_STEPS];
    __shared__ double lamS;
    __shared__ float yl[K_STEPS];
    if (tid < K_STEPS) {
        sa[tid] = (double)vec[AL8OFF + mat * K_STEPS + tid];
        sb[tid] = (tid < K_STEPS - 1)
            ? sqrt((double)vec[B28OFF + mat * (K_STEPS + 1) + tid + 1]) : 0.0;
    }
    __syncthreads();
    if (wv == 0) {
        double g = 0.0;
        if (lane < K_STEPS) {
            double bl = lane ? sb[lane - 1] : 0.0;
            g = sa[lane] + bl + sb[lane];
        }
#pragma unroll
        for (int off = 32; off; off >>= 1) {
            double o = __shfl_xor(g, off, 64);
            if (o > g) g = o;
        }
        double lo = 0.0, hi = g > 0.0 ? g : 1.0;
        for (int round = 0; round < 4; ++round) {
            double step = (hi - lo) / 65.0;
            double x = lo + step * (double)(lane + 1);
            int cnt = 0;
            double d = 1.0;
            for (int i = 0; i < K_STEPS; ++i) {
                double off2 = 0.0;
                if (i) { double b = sb[i - 1]; off2 = b * b / d; }
                d = (sa[i] - x) - off2;
                if (d == 0.0) d = -1e-300;
                if (d < 0.0) cnt++;
            }
            unsigned long long mask = __ballot(cnt >= K_STEPS);
            if (mask) {
                int idx = __ffsll(mask) - 1;
                hi = lo + step * (double)(idx + 1);
                lo = lo + step * (double)idx;
            } else {
                lo = lo + step * 64.0;
            }
        }
        if (lane == 0) lamS = 0.5 * (lo + hi);
    }
    __syncthreads();
    if (tid == 0) {
        double lam2 = lamS * (1.0 + 1e-7);
        double x[K_STEPS], cp[K_STEPS];
        for (int i = 0; i < K_STEPS; ++i) x[i] = 1.0;
        for (int it = 0; it < 3; ++it) {
            double d = sa[0] - lam2;
            if (fabs(d) < 1e-14) d = (d < 0.0 ? -1e-14 : 1e-14);
            cp[0] = sb[0] / d;
            x[0] = x[0] / d;
            for (int i = 1; i < K_STEPS; ++i) {
                double m = (sa[i] - lam2) - sb[i - 1] * cp[i - 1];
                if (fabs(m) < 1e-14) m = (m < 0.0 ? -1e-14 : 1e-14);
                if (i < K_STEPS - 1) cp[i] = sb[i] / m;
                x[i] = (x[i] - sb[i - 1] * x[i - 1]) / m;
            }
            for (int i = K_STEPS - 2; i >= 0; --i) x[i] -= cp[i] * x[i + 1];
            double nr = 0.0;
            for (int i = 0; i < K_STEPS; ++i) nr += x[i] * x[i];
            nr = 1.0 / sqrt(nr);
            for (int i = 0; i < K_STEPS; ++i) x[i] *= nr;
        }
        for (int i = 0; i < K_STEPS; ++i) yl[i] = (float)x[i];
    }
    __syncthreads();
    int qn = n >> 2;
    int c0 = q * qn, c1 = c0 + qn;
    const float* BAS = vec + BASOFF + mat * K_STEPS * VCAP;
    float ns = 0.0f;
    for (int c = c0 + tid; c < c1; c += 256) {
        float acc = 0.0f;
#pragma unroll
        for (int jj = 0; jj < K_STEPS; ++jj) acc += yl[jj] * BAS[jj * VCAP + c];
        vec[WOFF + mat * VCAP + c] = acc;
        ns += acc * acc;
    }
    float t = blockReduce(ns);
    if (tid == 0) atomicAdd(&vec[NS2OFF + mat], t);
}

// ||A v*||^2 on ORIGINAL fp32 matrices. 896 blocks x 1024 thr, wave-per-row.
__global__ __launch_bounds__(1024) void k_rq(const float* __restrict__ A0,
                                             const float* __restrict__ A1,
                                             const float* __restrict__ A2,
                                             float* __restrict__ vec) {
    __shared__ float shA[16];
    int bid = blockIdx.x, tid = threadIdx.x, wv = tid >> 6, lane = tid & 63;
    int mat, row0, n;
    if (bid < 256)      { mat = 0; n = 4096; row0 = bid << 4; }
    else if (bid < 768) { mat = 1; n = 2048; row0 = (bid - 256) << 4; }
    else                { mat = 2; n = 8192; row0 = (bid - 768) << 4; }
    const float* A = mat == 0 ? A0 : (mat == 1 ? A1 : A2);
    int row = row0 + wv;
    const float4* rp = (const float4*)(A + (size_t)row * n);
    const float4* vp = (const float4*)(vec + WOFF + mat * VCAP);
    int nf4 = n >> 2;
    float s = 0.0f;
    for (int c = lane; c < nf4; c += 64) {
        float4 a = rp[c], v = vp[c];
        s += a.x * v.x + a.y * v.y + a.z * v.z + a.w * v.w;
    }
#pragma unroll
    for (int off = 32; off; off >>= 1) s += __shfl_down(s, off, 64);
    if (lane == 0) shA[wv] = s * s;
    __syncthreads();
    if (tid == 0) {
        float t = 0.0f;
#pragma unroll
        for (int k = 0; k < 16; ++k) t += shA[k];
        atomicAdd(&vec[RQ2OFF + mat], t);
    }
}

__global__ void k_out(const float* __restrict__ vec, float* __restrict__ out) {
    if (threadIdx.x == 0 && blockIdx.x == 0) {
        float s = 0.0f;
        for (int m = 0; m < 3; ++m)
            s += sqrtf(vec[RQ2OFF + m] / vec[NS2OFF + m]);
        out[0] = 1e-4f * s;
    }
}

// ======================= fp32 last-resort fallback =======================
__global__ __launch_bounds__(1024) void k_init(float* vec) {
    int mat = blockIdx.x;
    int n = matN(mat);
    float* V0 = vec + mat * VCAP;
    float* V1 = vec + 3 * VCAP + mat * VCAP;
    float* Z  = vec + 9 * VCAP + mat * VCAP;
    int tid = threadIdx.x;
    float acc = 0.0f;
    for (int i = tid; i < VCAP; i += 1024) {
        float val = 0.0f;
        if (i < n) {
            unsigned h = (unsigned)(i * 2654435761u) ^ (0x9E3779B9u * (unsigned)(mat + 1));
            h ^= h >> 16; h *= 0x85EBCA6Bu; h ^= h >> 13; h *= 0xC2B2AE35u; h ^= h >> 16;
            val = ((h >> 8) * (1.0f / 16777216.0f)) - 0.5f;
            acc += val * val;
        }
        V1[i] = val; V0[i] = 0.0f; Z[i] = 0.0f;
    }
    float nrm2 = blockReduce(acc);
    float inv = rsqrtf(nrm2);
    for (int i = tid; i < n; i += 1024) V1[i] *= inv;
}

__global__ __launch_bounds__(256) void k_gemvA(const float* __restrict__ A0,
                                               const float* __restrict__ A1,
                                               const float* __restrict__ A2,
                                               float* __restrict__ vec) {
    const float* V1 = vec + 3 * VCAP;
    float* W = vec + 6 * VCAP;
    int wid = (int)((blockIdx.x * blockDim.x + threadIdx.x) >> 6);
    int lane = threadIdx.x & 63;
    int mat, row;
    if (wid < 4096)       { mat = 0; row = wid; }
    else if (wid < 12288) { mat = 1; row = wid - 4096; }
    else                  { mat = 2; row = wid - 12288; }
    const float* A = mat == 0 ? A0 : (mat == 1 ? A1 : A2);
    int n = matN(mat);
    const float4* rowp = (const float4*)(A + (size_t)row * n);
    const float4* vp = (const float4*)(V1 + mat * VCAP);
    int nf4 = n >> 2;
    float s = 0.0f;
    for (int t = lane; t < nf4; t += 64) {
        float4 a = rowp[t], v = vp[t];
        s += a.x * v.x + a.y * v.y + a.z * v.z + a.w * v.w;
    }
#pragma unroll
    for (int off = 32; off; off >>= 1) s += __shfl_down(s, off, 64);
    if (lane == 0) W[mat * VCAP + row] = s;
}

__global__ __launch_bounds__(256) void k_gemvT(const float* __restrict__ A0,
                                               const float* __restrict__ A1,
                                               const float* __restrict__ A2,
                                               float* __restrict__ vec) {
    const float* W = vec + 6 * VCAP;
    float* Z = vec + 9 * VCAP;
    int bid = blockIdx.x;
    int mat = bid >> 8;
    int t = bid & 255;
    int n = matN(mat);
    int nColTiles = n >> 10;
    int colTile = t % nColTiles;
    int rowChunk = t / nColTiles;
    int r0 = rowChunk * 64;
    int col = colTile * 1024 + threadIdx.x * 4;
    const float* A = mat == 0 ? A0 : (mat == 1 ? A1 : A2);
    __shared__ float wsh[64];
    if (threadIdx.x < 64) wsh[threadIdx.x] = W[mat * VCAP + r0 + threadIdx.x];
    __syncthreads();
    const float* Ab = A + (size_t)r0 * n + col;
    float4 s = {0.0f, 0.0f, 0.0f, 0.0f};
#pragma unroll 4
    for (int r = 0; r < 64; ++r) {
        float4 a = *(const float4*)(Ab + (size_t)r * n);
        float w = wsh[r];
        s.x += a.x * w; s.y += a.y * w; s.z += a.z * w; s.w += a.w * w;
    }
    float* Zm = Z + mat * VCAP + col;
    atomicAdd(Zm + 0, s.x);
    atomicAdd(Zm + 1, s.y);
    atomicAdd(Zm + 2, s.z);
    atomicAdd(Zm + 3, s.w);
}

__global__ __launch_bounds__(1024) void k_update(float* __restrict__ vec, int j) {
    int mat = blockIdx.x;
    int n = matN(mat);
    float* V0 = vec + mat * VCAP;
    float* V1 = vec + 3 * VCAP + mat * VCAP;
    float* Z  = vec + 9 * VCAP + mat * VCAP;
    float* ALPHA = vec + FB_AOFF;
    float* BETA  = ALPHA + 3 * K_STEPS;
    int tid = threadIdx.x;
    float acc = 0.0f;
    for (int i = tid; i < n; i += 1024) acc += V1[i] * Z[i];
    float alpha = blockReduce(acc);
    float bp = (j > 0) ? BETA[mat * K_STEPS + j - 1] : 0.0f;
    float acc2 = 0.0f;
    for (int i = tid; i < n; i += 1024) {
        float v1 = V1[i];
        float r = Z[i] - alpha * v1 - bp * V0[i];
        V0[i] = v1;
        Z[i] = r;
        acc2 += r * r;
    }
    float b2 = blockReduce(acc2);
    float beta = sqrtf(b2);
    float inv = (beta > 1e-20f) ? (1.0f / beta) : 0.0f;
    for (int i = tid; i < n; i += 1024) {
        V1[i] = Z[i] * inv;
        Z[i] = 0.0f;
    }
    if (tid == 0) {
        ALPHA[mat * K_STEPS + j] = alpha;
        BETA[mat * K_STEPS + j] = beta;
    }
}

__global__ __launch_bounds__(256) void k_final2(const float* __restrict__ vec,
                                                float* __restrict__ out) {
    __shared__ double sa[3][K_STEPS], sb[3][K_STEPS];
    __shared__ double sig[3];
    int tid = threadIdx.x, wid = tid >> 6, lane = tid & 63;
    if (wid < 3 && lane < K_STEPS) {
        const float* AL = vec + FB_AOFF + wid * K_STEPS;
        const float* BE = vec + FB_AOFF + 3 * K_STEPS + wid * K_STEPS;
        sa[wid][lane] = (double)AL[lane];
        sb[wid][lane] = (lane < K_STEPS - 1) ? (double)BE[lane] : 0.0;
    }
    __syncthreads();
    if (wid < 3) {
        double g = 0.0;
        if (lane < K_STEPS) {
            double bl_ = lane ? sb[wid][lane - 1] : 0.0;
            g = sa[wid][lane] + bl_ + sb[wid][lane];
        }
#pragma unroll
        for (int off = 32; off; off >>= 1) {
            double o = __shfl_xor(g, off, 64);
            if (o > g) g = o;
        }
        double lo = 0.0, hi = g > 0.0 ? g : 1.0;
        for (int round = 0; round < 4; ++round) {
            double step = (hi - lo) / 65.0;
            double x = lo + step * (double)(lane + 1);
            int cnt = 0;
            double d = 1.0;
            for (int i = 0; i < K_STEPS; ++i) {
                double off2 = 0.0;
                if (i) { double b = sb[wid][i - 1]; off2 = b * b / d; }
                d = (sa[wid][i] - x) - off2;
                if (d == 0.0) d = -1e-300;
                if (d < 0.0) cnt++;
            }
            unsigned long long mask = __ballot(cnt >= K_STEPS);
            if (mask) {
                int idx = __ffsll(mask) - 1;
                hi = lo + step * (double)(idx + 1);
                lo = lo + step * (double)idx;
            } else {
                lo = lo + step * 64.0;
            }
        }
        if (lane == 0) {
            double lam = 0.5 * (lo + hi);
            sig[wid] = sqrt(lam > 0.0 ? lam : 0.0);
        }
    }
    __syncthreads();
    if (tid == 0) out[0] = (float)(1e-4 * (sig[0] + sig[1] + sig[2]));
}

extern "C" void kernel_launch(void* const* d_in, const int* in_sizes, int n_in,
                              void* d_out, int out_size, void* d_ws, size_t ws_size,
                              hipStream_t stream) {
    const float* A0 = (const float*)d_in[0];
    const float* A1 = (const float*)d_in[1];
    const float* A2 = (const float*)d_in[2];
    float* out = (float*)d_out;

    const size_t f8_bytes = (size_t)3 * MELEMS;
    const size_t vec8_bytes = (size_t)VEC8_FLOATS * 4 + 1024;

    if (ws_size >= f8_bytes + vec8_bytes) {
        u32* F = (u32*)d_ws;
        float* vec = (float*)((char*)d_ws + f8_bytes);
        hipLaunchKernelGGL(k_conv_init, dim3(3076), dim3(256), 0, stream, A0, A1, A2, F, vec);
        for (int j = 0; j < K_STEPS; ++j) {
            hipLaunchKernelGGL(k_fusedAT, dim3(768), dim3(256), 0, stream, F, vec, j);
        }
        hipLaunchKernelGGL(k_final3, dim3(12), dim3(256), 0, stream, vec);
        hipLaunchKernelGGL(k_rq, dim3(896), dim3(1024), 0, stream, A0, A1, A2, vec);
        hipLaunchKernelGGL(k_out, dim3(1), dim3(64), 0, stream, vec, out);
    } else {
        float* vec = (float*)d_ws;
        hipLaunchKernelGGL(k_init, dim3(3), dim3(1024), 0, stream, vec);
        for (int j = 0; j < K_STEPS; ++j) {
            hipLaunchKernelGGL(k_gemvA, dim3(3584), dim3(256), 0, stream, A0, A1, A2, vec);
            hipLaunchKernelGGL(k_gemvT, dim3(768), dim3(256), 0, stream, A0, A1, A2, vec);
            hipLaunchKernelGGL(k_update, dim3(3), dim3(1024), 0, stream, vec, j);
        }
        hipLaunchKernelGGL(k_final2, dim3(1), dim3(256), 0, stream, vec, out);
    }
}

// Round 11
// 1464.033 us; speedup vs baseline: 1.3042x; 1.3042x over previous
//
#include <hip/hip_runtime.h>
#include <math.h>

// Spectral regularization: 1e-4 * (sigma_max(w1) + sigma_max(w2) + sigma_max(w3))
// Lanczos (K=24, no reorth) on B = F^T F, F = fp8-e4m3(A) (50 MB, L3-resident).
// Per step: k_fusedAT (32KB row-tile per block: phase1 row dots w=F u + alpha,
// phase2 L2/L3-hot re-read -> column partials, plain stores), then k_stepR8
// (reduce 512 partials + alpha/beta update). Ritz vector v* measured on fp32 A:
// sigma = ||A v*|| / ||v*|| (variational, second-order accurate).
//
// Shapes (row-major): w1 4096x4096, w2 8192x2048, w3 2048x8192 (each 16777216)

#define K_STEPS 24
#define VCAP 8192
#define MELEMS 16777216
#define NCHUNK 512

// fp8-path vec layout (floats)
#define UOFF   0                                  // u_j (unnormalized residual), 3*VCAP
#define V0OFF  (3 * VCAP)                         // v_{j-1} normalized
#define WOFF   (6 * VCAP)                         // w; later v*
#define P8OFF  (9 * VCAP)                         // partials: 512 chunks/matrix, 28 MB
#define P8TOT  7340032
#define BASOFF (P8OFF + P8TOT)                    // basis, 3*K*VCAP
#define AL8OFF (BASOFF + 3 * K_STEPS * VCAP)      // ALPHA [3][K]
#define B28OFF (AL8OFF + 3 * K_STEPS)             // B2 [3][K+1]
#define NS2OFF (B28OFF + 3 * (K_STEPS + 1))       // ||v*||^2 [3]
#define RQ2OFF (NS2OFF + 3)                       // ||A v*||^2 [3]
#define VEC8_FLOATS (RQ2OFF + 3)

// fp32 fallback layout
#define FB_AOFF (12 * VCAP)

typedef unsigned int u32;
typedef float f32x2 __attribute__((ext_vector_type(2)));

__device__ __forceinline__ int matN(int m) { return m == 0 ? 4096 : (m == 1 ? 2048 : 8192); }
__device__ __forceinline__ int pbase(int m) { return m == 0 ? 0 : (m == 1 ? 2097152 : 3145728); }

__device__ __forceinline__ f32x2 up8(u32 w, bool hi) {
    return hi ? __builtin_amdgcn_cvt_pk_f32_fp8(w, true)
              : __builtin_amdgcn_cvt_pk_f32_fp8(w, false);
}

__device__ float blockReduce(float v) {
    __shared__ float sh[16];
    int lane = threadIdx.x & 63, wid = threadIdx.x >> 6;
#pragma unroll
    for (int off = 32; off; off >>= 1) v += __shfl_down(v, off, 64);
    if (lane == 0) sh[wid] = v;
    __syncthreads();
    if (wid == 0) {
        int nw = (blockDim.x + 63) >> 6;
        float x = (lane < nw) ? sh[lane] : 0.0f;
#pragma unroll
        for (int off = 8; off; off >>= 1) x += __shfl_down(x, off, 64);
        if (lane == 0) sh[0] = x;
    }
    __syncthreads();
    float r = sh[0];
    __syncthreads();
    return r;
}

// ======================= fp8 path =======================

// convert (blocks 0..3071; fully coalesced: one float4 read -> one u32 write
// per lane per iter) + init (tail blocks)
__global__ __launch_bounds__(256) void k_conv_init(const float* __restrict__ A0,
                                                   const float* __restrict__ A1,
                                                   const float* __restrict__ A2,
                                                   u32* __restrict__ F,
                                                   float* __restrict__ vec) {
    int bid = blockIdx.x, tid = threadIdx.x;
    if (bid < 3072) {
        const int per4 = MELEMS >> 2;             // 2^22 float4 per matrix
        const int nv4 = 3 * per4;
        for (int i = bid * 256 + tid; i < nv4; i += 3072 * 256) {
            int mat = i >> 22;
            int iv = i & (per4 - 1);
            const float4* Af = (const float4*)(mat == 0 ? A0 : (mat == 1 ? A1 : A2));
            float4 a = Af[iv];
            u32 o = __builtin_amdgcn_cvt_pk_fp8_f32(a.x, a.y, 0u, false);
            o = __builtin_amdgcn_cvt_pk_fp8_f32(a.z, a.w, o, true);
            F[i] = o;                             // i == mat*(MELEMS/4) + iv
        }
    } else if (bid < 3075) {
        int mat = bid - 3072, n = matN(mat);
        float acc = 0.0f;
        for (int i = tid; i < VCAP; i += 256) {
            float val = 0.0f;
            if (i < n) {
                unsigned h = (unsigned)(i * 2654435761u) ^ (0x9E3779B9u * (unsigned)(mat + 1));
                h ^= h >> 16; h *= 0x85EBCA6Bu; h ^= h >> 13; h *= 0xC2B2AE35u; h ^= h >> 16;
                val = ((h >> 8) * (1.0f / 16777216.0f)) - 0.5f;
                acc += val * val;
            }
            vec[UOFF + mat * VCAP + i] = val;
            vec[V0OFF + mat * VCAP + i] = 0.0f;
        }
        float nrm2 = blockReduce(acc);
        if (tid == 0) vec[B28OFF + mat * (K_STEPS + 1)] = nrm2;
    } else {
        for (int i = tid; i < 3 * K_STEPS; i += 256) vec[AL8OFF + i] = 0.0f;
        for (int i = tid; i < 3 * (K_STEPS + 1); i += 256)
            if (i % (K_STEPS + 1)) vec[B28OFF + i] = 0.0f;
        if (tid < 3) { vec[NS2OFF + tid] = 0.0f; vec[RQ2OFF + tid] = 0.0f; }
    }
}

// ---- fused step kernel: block = R rows x N cols (32 KB fp8) ----
// phase 1: w_r = <F_row, u> * inv (uint2 granularity), alpha += ||w||^2.
// phase 2: re-read own tile (L2/L3-hot) column-wise -> partial z slice.
template <int N, int R>
__device__ void fusedAT_body(const u32* __restrict__ Fm, float* __restrict__ vec,
                             int mat, int chunk, int j,
                             float* __restrict__ Pm, float* wsh, float* shA) {
    constexpr int RPW = R / 4;        // rows per wave (4 waves, R>=4 for all mats)
    constexpr int NU2 = N >> 3;       // uint2 per row
    constexpr int KK  = N >> 11;      // 2048-col groups (phase 2)
    const int tid = threadIdx.x, wv = tid >> 6, lane = tid & 63;
    const int row0 = chunk * R;

    // ---- phase 1: row dots ----
    float inv = rsqrtf(vec[B28OFF + mat * (K_STEPS + 1) + j]);
    const float4* vp = (const float4*)(vec + UOFF + mat * VCAP);
    float aacc = 0.0f;
#pragma unroll
    for (int rr = 0; rr < RPW; ++rr) {
        int rl = wv * RPW + rr;
        const uint2* rp = (const uint2*)((const char*)Fm + (size_t)(row0 + rl) * N);
        float s = 0.0f;
#pragma unroll
        for (int c = lane; c < NU2; c += 64) {
            uint2 a = rp[c];
            float4 u0 = vp[2 * c + 0], u1 = vp[2 * c + 1];
            f32x2 f0 = up8(a.x, false), f1 = up8(a.x, true);
            f32x2 f2 = up8(a.y, false), f3 = up8(a.y, true);
            s += f0[0] * u0.x + f0[1] * u0.y + f1[0] * u0.z + f1[1] * u0.w
               + f2[0] * u1.x + f2[1] * u1.y + f3[0] * u1.z + f3[1] * u1.w;
        }
#pragma unroll
        for (int off = 32; off; off >>= 1) s += __shfl_down(s, off, 64);
        if (lane == 0) { wsh[rl] = s * inv; aacc += s * s; }
    }
    if (lane == 0) shA[wv] = aacc;
    __syncthreads();
    if (tid == 0)
        atomicAdd(&vec[AL8OFF + mat * K_STEPS + j],
                  (shA[0] + shA[1] + shA[2] + shA[3]) * inv * inv);

    // ---- phase 2: column partials (tile cache-hot) ----
#pragma unroll
    for (int kk = 0; kk < KK; ++kk) {
        int col = (tid + (kk << 8)) << 3;
        const char* bb = (const char*)Fm + (size_t)row0 * N + col;
        float a0 = 0, a1 = 0, a2 = 0, a3 = 0, a4 = 0, a5 = 0, a6 = 0, a7 = 0;
#pragma unroll
        for (int r = 0; r < R; ++r) {
            uint2 a = *(const uint2*)(bb + (size_t)r * N);
            f32x2 f0 = up8(a.x, false), f1 = up8(a.x, true);
            f32x2 f2 = up8(a.y, false), f3 = up8(a.y, true);
            float w = wsh[r];
            a0 += f0[0] * w; a1 += f0[1] * w; a2 += f1[0] * w; a3 += f1[1] * w;
            a4 += f2[0] * w; a5 += f2[1] * w; a6 += f3[0] * w; a7 += f3[1] * w;
        }
        float* Pp = Pm + (size_t)chunk * N + col;
        float4 lo = {a0, a1, a2, a3}, hi = {a4, a5, a6, a7};
        ((float4*)Pp)[0] = lo;
        ((float4*)Pp)[1] = hi;
    }
}

__global__ __launch_bounds__(256, 8) void k_fusedAT(const u32* __restrict__ F,
                                                    float* __restrict__ vec, int j) {
    __shared__ float wsh[32];
    __shared__ float shA[4];
    int bid = blockIdx.x;
    if (bid < 512) {
        fusedAT_body<4096, 8>((const u32*)((const char*)F + (size_t)0 * MELEMS),
                              vec, 0, bid, j, vec + P8OFF + pbase(0), wsh, shA);
    } else if (bid < 1024) {
        fusedAT_body<2048, 16>((const u32*)((const char*)F + (size_t)1 * MELEMS),
                               vec, 1, bid - 512, j, vec + P8OFF + pbase(1), wsh, shA);
    } else {
        fusedAT_body<8192, 4>((const u32*)((const char*)F + (size_t)2 * MELEMS),
                              vec, 2, bid - 1024, j, vec + P8OFF + pbase(2), wsh, shA);
    }
}

// reduce 512 partials/column; r = z - alpha v - beta_prev v0; basis write; beta^2.
__global__ __launch_bounds__(256) void k_stepR8(float* __restrict__ vec, int j) {
    int bid = blockIdx.x, tid = threadIdx.x;
    int mat, col0, n;
    if (bid < 16)      { mat = 0; n = 4096; col0 = bid << 8; }
    else if (bid < 24) { mat = 1; n = 2048; col0 = (bid - 16) << 8; }
    else               { mat = 2; n = 8192; col0 = (bid - 24) << 8; }
    int col = col0 + tid;
    const float* P = vec + P8OFF + pbase(mat);
    float z = 0.0f;
#pragma unroll 8
    for (int rc = 0; rc < NCHUNK; ++rc) z += P[(size_t)rc * n + col];
    float b2p = vec[B28OFF + mat * (K_STEPS + 1) + j];
    float bp = sqrtf(b2p);
    float inv = 1.0f / bp;
    float alpha = vec[AL8OFF + mat * K_STEPS + j];
    int g = mat * VCAP + col;
    float v1 = vec[UOFF + g] * inv;
    float r = z - alpha * v1 - bp * vec[V0OFF + g];
    vec[V0OFF + g] = v1;
    vec[UOFF + g] = r;
    vec[BASOFF + (mat * K_STEPS + j) * VCAP + col] = v1;
    float rr2 = blockReduce(r * r);
    if (tid == 0) atomicAdd(&vec[B28OFF + mat * (K_STEPS + 1) + j + 1], rr2);
}

// Sturm lambda_max + 3 inverse iterations -> y ; v* = Basis^T y (quarter per block).
__global__ __launch_bounds__(256) void k_final3(float* __restrict__ vec) {
    int bid = blockIdx.x;
    int mat = bid >> 2, q = bid & 3, tid = threadIdx.x, lane = tid & 63, wv = tid >> 6;
    int n = matN(mat);
    __shared__ double sa[K_STEPS], sb[K_STEPS];
    __shared__ double lamS;
    __shared__ float yl[K_STEPS];
    if (tid < K_STEPS) {
        sa[tid] = (double)vec[AL8OFF + mat * K_STEPS + tid];
        sb[tid] = (tid < K_STEPS - 1)
            ? sqrt((double)vec[B28OFF + mat * (K_STEPS + 1) + tid + 1]) : 0.0;
    }
    __syncthreads();
    if (wv == 0) {
        double g = 0.0;
        if (lane < K_STEPS) {
            double bl = lane ? sb[lane - 1] : 0.0;
            g = sa[lane] + bl + sb[lane];
        }
#pragma unroll
        for (int off = 32; off; off >>= 1) {
            double o = __shfl_xor(g, off, 64);
            if (o > g) g = o;
        }
        double lo = 0.0, hi = g > 0.0 ? g : 1.0;
        for (int round = 0; round < 4; ++round) {
            double step = (hi - lo) / 65.0;
            double x = lo + step * (double)(lane + 1);
            int cnt = 0;
            double d = 1.0;
            for (int i = 0; i < K_STEPS; ++i) {
                double off2 = 0.0;
                if (i) { double b = sb[i - 1]; off2 = b * b / d; }
                d = (sa[i] - x) - off2;
                if (d == 0.0) d = -1e-300;
                if (d < 0.0) cnt++;
            }
            unsigned long long mask = __ballot(cnt >= K_STEPS);
            if (mask) {
                int idx = __ffsll(mask) - 1;
                hi = lo + step * (double)(idx + 1);
                lo = lo + step * (double)idx;
            } else {
                lo = lo + step * 64.0;
            }
        }
        if (lane == 0) lamS = 0.5 * (lo + hi);
    }
    __syncthreads();
    if (tid == 0) {
        double lam2 = lamS * (1.0 + 1e-7);
        double x[K_STEPS], cp[K_STEPS];
        for (int i = 0; i < K_STEPS; ++i) x[i] = 1.0;
        for (int it = 0; it < 3; ++it) {
            double d = sa[0] - lam2;
            if (fabs(d) < 1e-14) d = (d < 0.0 ? -1e-14 : 1e-14);
            cp[0] = sb[0] / d;
            x[0] = x[0] / d;
            for (int i = 1; i < K_STEPS; ++i) {
                double m = (sa[i] - lam2) - sb[i - 1] * cp[i - 1];
                if (fabs(m) < 1e-14) m = (m < 0.0 ? -1e-14 : 1e-14);
                if (i < K_STEPS - 1) cp[i] = sb[i] / m;
                x[i] = (x[i] - sb[i - 1] * x[i - 1]) / m;
            }
            for (int i = K_STEPS - 2; i >= 0; --i) x[i] -= cp[i] * x[i + 1];
            double nr = 0.0;
            for (int i = 0; i < K_STEPS; ++i) nr += x[i] * x[i];
            nr = 1.0 / sqrt(nr);
            for (int i = 0; i < K_STEPS; ++i) x[i] *= nr;
        }
        for (int i = 0; i < K_STEPS; ++i) yl[i] = (float)x[i];
    }
    __syncthreads();
    int qn = n >> 2;
    int c0 = q * qn, c1 = c0 + qn;
    const float* BAS = vec + BASOFF + mat * K_STEPS * VCAP;
    float ns = 0.0f;
    for (int c = c0 + tid; c < c1; c += 256) {
        float acc = 0.0f;
#pragma unroll
        for (int jj = 0; jj < K_STEPS; ++jj) acc += yl[jj] * BAS[jj * VCAP + c];
        vec[WOFF + mat * VCAP + c] = acc;
        ns += acc * acc;
    }
    float t = blockReduce(ns);
    if (tid == 0) atomicAdd(&vec[NS2OFF + mat], t);
}

// ||A v*||^2 on ORIGINAL fp32 matrices. 896 blocks x 1024 thr, wave-per-row.
__global__ __launch_bounds__(1024) void k_rq(const float* __restrict__ A0,
                                             const float* __restrict__ A1,
                                             const float* __restrict__ A2,
                                             float* __restrict__ vec) {
    __shared__ float shA[16];
    int bid = blockIdx.x, tid = threadIdx.x, wv = tid >> 6, lane = tid & 63;
    int mat, row0, n;
    if (bid < 256)      { mat = 0; n = 4096; row0 = bid << 4; }
    else if (bid < 768) { mat = 1; n = 2048; row0 = (bid - 256) << 4; }
    else                { mat = 2; n = 8192; row0 = (bid - 768) << 4; }
    const float* A = mat == 0 ? A0 : (mat == 1 ? A1 : A2);
    int row = row0 + wv;
    const float4* rp = (const float4*)(A + (size_t)row * n);
    const float4* vp = (const float4*)(vec + WOFF + mat * VCAP);
    int nf4 = n >> 2;
    float s = 0.0f;
    for (int c = lane; c < nf4; c += 64) {
        float4 a = rp[c], v = vp[c];
        s += a.x * v.x + a.y * v.y + a.z * v.z + a.w * v.w;
    }
#pragma unroll
    for (int off = 32; off; off >>= 1) s += __shfl_down(s, off, 64);
    if (lane == 0) shA[wv] = s * s;
    __syncthreads();
    if (tid == 0) {
        float t = 0.0f;
#pragma unroll
        for (int k = 0; k < 16; ++k) t += shA[k];
        atomicAdd(&vec[RQ2OFF + mat], t);
    }
}

__global__ void k_out(const float* __restrict__ vec, float* __restrict__ out) {
    if (threadIdx.x == 0 && blockIdx.x == 0) {
        float s = 0.0f;
        for (int m = 0; m < 3; ++m)
            s += sqrtf(vec[RQ2OFF + m] / vec[NS2OFF + m]);
        out[0] = 1e-4f * s;
    }
}

// ======================= fp32 last-resort fallback =======================
__global__ __launch_bounds__(1024) void k_init(float* vec) {
    int mat = blockIdx.x;
    int n = matN(mat);
    float* V0 = vec + mat * VCAP;
    float* V1 = vec + 3 * VCAP + mat * VCAP;
    float* Z  = vec + 9 * VCAP + mat * VCAP;
    int tid = threadIdx.x;
    float acc = 0.0f;
    for (int i = tid; i < VCAP; i += 1024) {
        float val = 0.0f;
        if (i < n) {
            unsigned h = (unsigned)(i * 2654435761u) ^ (0x9E3779B9u * (unsigned)(mat + 1));
            h ^= h >> 16; h *= 0x85EBCA6Bu; h ^= h >> 13; h *= 0xC2B2AE35u; h ^= h >> 16;
            val = ((h >> 8) * (1.0f / 16777216.0f)) - 0.5f;
            acc += val * val;
        }
        V1[i] = val; V0[i] = 0.0f; Z[i] = 0.0f;
    }
    float nrm2 = blockReduce(acc);
    float inv = rsqrtf(nrm2);
    for (int i = tid; i < n; i += 1024) V1[i] *= inv;
}

__global__ __launch_bounds__(256) void k_gemvA(const float* __restrict__ A0,
                                               const float* __restrict__ A1,
                                               const float* __restrict__ A2,
                                               float* __restrict__ vec) {
    const float* V1 = vec + 3 * VCAP;
    float* W = vec + 6 * VCAP;
    int wid = (int)((blockIdx.x * blockDim.x + threadIdx.x) >> 6);
    int lane = threadIdx.x & 63;
    int mat, row;
    if (wid < 4096)       { mat = 0; row = wid; }
    else if (wid < 12288) { mat = 1; row = wid - 4096; }
    else                  { mat = 2; row = wid - 12288; }
    const float* A = mat == 0 ? A0 : (mat == 1 ? A1 : A2);
    int n = matN(mat);
    const float4* rowp = (const float4*)(A + (size_t)row * n);
    const float4* vp = (const float4*)(V1 + mat * VCAP);
    int nf4 = n >> 2;
    float s = 0.0f;
    for (int t = lane; t < nf4; t += 64) {
        float4 a = rowp[t], v = vp[t];
        s += a.x * v.x + a.y * v.y + a.z * v.z + a.w * v.w;
    }
#pragma unroll
    for (int off = 32; off; off >>= 1) s += __shfl_down(s, off, 64);
    if (lane == 0) W[mat * VCAP + row] = s;
}

__global__ __launch_bounds__(256) void k_gemvT(const float* __restrict__ A0,
                                               const float* __restrict__ A1,
                                               const float* __restrict__ A2,
                                               float* __restrict__ vec) {
    const float* W = vec + 6 * VCAP;
    float* Z = vec + 9 * VCAP;
    int bid = blockIdx.x;
    int mat = bid >> 8;
    int t = bid & 255;
    int n = matN(mat);
    int nColTiles = n >> 10;
    int colTile = t % nColTiles;
    int rowChunk = t / nColTiles;
    int r0 = rowChunk * 64;
    int col = colTile * 1024 + threadIdx.x * 4;
    const float* A = mat == 0 ? A0 : (mat == 1 ? A1 : A2);
    __shared__ float wsh[64];
    if (threadIdx.x < 64) wsh[threadIdx.x] = W[mat * VCAP + r0 + threadIdx.x];
    __syncthreads();
    const float* Ab = A + (size_t)r0 * n + col;
    float4 s = {0.0f, 0.0f, 0.0f, 0.0f};
#pragma unroll 4
    for (int r = 0; r < 64; ++r) {
        float4 a = *(const float4*)(Ab + (size_t)r * n);
        float w = wsh[r];
        s.x += a.x * w; s.y += a.y * w; s.z += a.z * w; s.w += a.w * w;
    }
    float* Zm = Z + mat * VCAP + col;
    atomicAdd(Zm + 0, s.x);
    atomicAdd(Zm + 1, s.y);
    atomicAdd(Zm + 2, s.z);
    atomicAdd(Zm + 3, s.w);
}

__global__ __launch_bounds__(1024) void k_update(float* __restrict__ vec, int j) {
    int mat = blockIdx.x;
    int n = matN(mat);
    float* V0 = vec + mat * VCAP;
    float* V1 = vec + 3 * VCAP + mat * VCAP;
    float* Z  = vec + 9 * VCAP + mat * VCAP;
    float* ALPHA = vec + FB_AOFF;
    float* BETA  = ALPHA + 3 * K_STEPS;
    int tid = threadIdx.x;
    float acc = 0.0f;
    for (int i = tid; i < n; i += 1024) acc += V1[i] * Z[i];
    float alpha = blockReduce(acc);
    float bp = (j > 0) ? BETA[mat * K_STEPS + j - 1] : 0.0f;
    float acc2 = 0.0f;
    for (int i = tid; i < n; i += 1024) {
        float v1 = V1[i];
        float r = Z[i] - alpha * v1 - bp * V0[i];
        V0[i] = v1;
        Z[i] = r;
        acc2 += r * r;
    }
    float b2 = blockReduce(acc2);
    float beta = sqrtf(b2);
    float inv = (beta > 1e-20f) ? (1.0f / beta) : 0.0f;
    for (int i = tid; i < n; i += 1024) {
        V1[i] = Z[i] * inv;
        Z[i] = 0.0f;
    }
    if (tid == 0) {
        ALPHA[mat * K_STEPS + j] = alpha;
        BETA[mat * K_STEPS + j] = beta;
    }
}

__global__ __launch_bounds__(256) void k_final2(const float* __restrict__ vec,
                                                float* __restrict__ out) {
    __shared__ double sa[3][K_STEPS], sb[3][K_STEPS];
    __shared__ double sig[3];
    int tid = threadIdx.x, wid = tid >> 6, lane = tid & 63;
    if (wid < 3 && lane < K_STEPS) {
        const float* AL = vec + FB_AOFF + wid * K_STEPS;
        const float* BE = vec + FB_AOFF + 3 * K_STEPS + wid * K_STEPS;
        sa[wid][lane] = (double)AL[lane];
        sb[wid][lane] = (lane < K_STEPS - 1) ? (double)BE[lane] : 0.0;
    }
    __syncthreads();
    if (wid < 3) {
        double g = 0.0;
        if (lane < K_STEPS) {
            double bl_ = lane ? sb[wid][lane - 1] : 0.0;
            g = sa[wid][lane] + bl_ + sb[wid][lane];
        }
#pragma unroll
        for (int off = 32; off; off >>= 1) {
            double o = __shfl_xor(g, off, 64);
            if (o > g) g = o;
        }
        double lo = 0.0, hi = g > 0.0 ? g : 1.0;
        for (int round = 0; round < 4; ++round) {
            double step = (hi - lo) / 65.0;
            double x = lo + step * (double)(lane + 1);
            int cnt = 0;
            double d = 1.0;
            for (int i = 0; i < K_STEPS; ++i) {
                double off2 = 0.0;
                if (i) { double b = sb[wid][i - 1]; off2 = b * b / d; }
                d = (sa[wid][i] - x) - off2;
                if (d == 0.0) d = -1e-300;
                if (d < 0.0) cnt++;
            }
            unsigned long long mask = __ballot(cnt >= K_STEPS);
            if (mask) {
                int idx = __ffsll(mask) - 1;
                hi = lo + step * (double)(idx + 1);
                lo = lo + step * (double)idx;
            } else {
                lo = lo + step * 64.0;
            }
        }
        if (lane == 0) {
            double lam = 0.5 * (lo + hi);
            sig[wid] = sqrt(lam > 0.0 ? lam : 0.0);
        }
    }
    __syncthreads();
    if (tid == 0) out[0] = (float)(1e-4 * (sig[0] + sig[1] + sig[2]));
}

extern "C" void kernel_launch(void* const* d_in, const int* in_sizes, int n_in,
                              void* d_out, int out_size, void* d_ws, size_t ws_size,
                              hipStream_t stream) {
    const float* A0 = (const float*)d_in[0];
    const float* A1 = (const float*)d_in[1];
    const float* A2 = (const float*)d_in[2];
    float* out = (float*)d_out;

    const size_t f8_bytes = (size_t)3 * MELEMS;
    const size_t vec8_bytes = (size_t)VEC8_FLOATS * 4 + 1024;

    if (ws_size >= f8_bytes + vec8_bytes) {
        u32* F = (u32*)d_ws;
        float* vec = (float*)((char*)d_ws + f8_bytes);
        hipLaunchKernelGGL(k_conv_init, dim3(3076), dim3(256), 0, stream, A0, A1, A2, F, vec);
        for (int j = 0; j < K_STEPS; ++j) {
            hipLaunchKernelGGL(k_fusedAT, dim3(1536), dim3(256), 0, stream, F, vec, j);
            hipLaunchKernelGGL(k_stepR8, dim3(56), dim3(256), 0, stream, vec, j);
        }
        hipLaunchKernelGGL(k_final3, dim3(12), dim3(256), 0, stream, vec);
        hipLaunchKernelGGL(k_rq, dim3(896), dim3(1024), 0, stream, A0, A1, A2, vec);
        hipLaunchKernelGGL(k_out, dim3(1), dim3(64), 0, stream, vec, out);
    } else {
        float* vec = (float*)d_ws;
        hipLaunchKernelGGL(k_init, dim3(3), dim3(1024), 0, stream, vec);
        for (int j = 0; j < K_STEPS; ++j) {
            hipLaunchKernelGGL(k_gemvA, dim3(3584), dim3(256), 0, stream, A0, A1, A2, vec);
            hipLaunchKernelGGL(k_gemvT, dim3(768), dim3(256), 0, stream, A0, A1, A2, vec);
            hipLaunchKernelGGL(k_update, dim3(3), dim3(1024), 0, stream, vec, j);
        }
        hipLaunchKernelGGL(k_final2, dim3(1), dim3(256), 0, stream, vec, out);
    }
}

// Round 12
// 892.386 us; speedup vs baseline: 2.1396x; 1.6406x over previous
//
#include <hip/hip_runtime.h>
#include <math.h>

// Spectral regularization: 1e-4 * (sigma_max(w1) + sigma_max(w2) + sigma_max(w3))
// Lanczos (K=24, no reorth) on B = F^T F, F = fp8-e4m3(A) (50 MB, L3-resident).
// Step 0: k_fusedAT0 converts fp32 A -> F inline (dots computed from the packed
// fp8 values -> bit-identical to the separate-convert path). Steps 1..K-1:
// k_fusedAT (R8-proven 64KB row-tile: phase1 row dots w=F u + alpha, phase2
// L2/L3-hot re-read -> column partials). k_stepR8 reduces 256 partials +
// alpha/beta update. Ritz vector v* measured on fp32 A: sigma = ||A v*||/||v*||.
//
// Shapes (row-major): w1 4096x4096, w2 8192x2048, w3 2048x8192 (each 16777216)

#define K_STEPS 24
#define VCAP 8192
#define MELEMS 16777216
#define NCHUNK 256

// fp8-path vec layout (floats)
#define UOFF   0                                  // u_j (unnormalized residual), 3*VCAP
#define V0OFF  (3 * VCAP)                         // v_{j-1} normalized
#define WOFF   (6 * VCAP)                         // w; later v*
#define P8OFF  (9 * VCAP)                         // partials: 256 chunks/matrix, 14 MB
#define P8TOT  3670016
#define BASOFF (P8OFF + P8TOT)                    // basis, 3*K*VCAP
#define AL8OFF (BASOFF + 3 * K_STEPS * VCAP)      // ALPHA [3][K]
#define B28OFF (AL8OFF + 3 * K_STEPS)             // B2 [3][K+1]
#define NS2OFF (B28OFF + 3 * (K_STEPS + 1))       // ||v*||^2 [3]
#define RQ2OFF (NS2OFF + 3)                       // ||A v*||^2 [3]
#define VEC8_FLOATS (RQ2OFF + 3)

// fp32 fallback layout
#define FB_AOFF (12 * VCAP)

typedef unsigned int u32;
typedef float f32x2 __attribute__((ext_vector_type(2)));

__device__ __forceinline__ int matN(int m) { return m == 0 ? 4096 : (m == 1 ? 2048 : 8192); }
__device__ __forceinline__ int pbase(int m) { return m == 0 ? 0 : (m == 1 ? 1048576 : 1572864); }

__device__ __forceinline__ f32x2 up8(u32 w, bool hi) {
    return hi ? __builtin_amdgcn_cvt_pk_f32_fp8(w, true)
              : __builtin_amdgcn_cvt_pk_f32_fp8(w, false);
}

__device__ float blockReduce(float v) {
    __shared__ float sh[16];
    int lane = threadIdx.x & 63, wid = threadIdx.x >> 6;
#pragma unroll
    for (int off = 32; off; off >>= 1) v += __shfl_down(v, off, 64);
    if (lane == 0) sh[wid] = v;
    __syncthreads();
    if (wid == 0) {
        int nw = (blockDim.x + 63) >> 6;
        float x = (lane < nw) ? sh[lane] : 0.0f;
#pragma unroll
        for (int off = 8; off; off >>= 1) x += __shfl_down(x, off, 64);
        if (lane == 0) sh[0] = x;
    }
    __syncthreads();
    float r = sh[0];
    __syncthreads();
    return r;
}

// ======================= fp8 path =======================

__global__ __launch_bounds__(256) void k_init8(float* vec) {
    int bid = blockIdx.x, tid = threadIdx.x;
    if (bid < 3) {
        int mat = bid, n = matN(mat);
        float acc = 0.0f;
        for (int i = tid; i < VCAP; i += 256) {
            float val = 0.0f;
            if (i < n) {
                unsigned h = (unsigned)(i * 2654435761u) ^ (0x9E3779B9u * (unsigned)(mat + 1));
                h ^= h >> 16; h *= 0x85EBCA6Bu; h ^= h >> 13; h *= 0xC2B2AE35u; h ^= h >> 16;
                val = ((h >> 8) * (1.0f / 16777216.0f)) - 0.5f;
                acc += val * val;
            }
            vec[UOFF + mat * VCAP + i] = val;
            vec[V0OFF + mat * VCAP + i] = 0.0f;
        }
        float nrm2 = blockReduce(acc);
        if (tid == 0) vec[B28OFF + mat * (K_STEPS + 1)] = nrm2;
    } else {
        for (int i = tid; i < 3 * K_STEPS; i += 256) vec[AL8OFF + i] = 0.0f;
        for (int i = tid; i < 3 * (K_STEPS + 1); i += 256)
            if (i % (K_STEPS + 1)) vec[B28OFF + i] = 0.0f;
        if (tid < 3) { vec[NS2OFF + tid] = 0.0f; vec[RQ2OFF + tid] = 0.0f; }
    }
}

// ---- step-0 kernel: convert + step fused ----
// phase 1: read fp32 A rows, pack fp8 -> store F, unpack the PACKED values and
// dot with u (bit-identical to reading F). phase 2: column partials from F.
template <int N, int R>
__device__ void fusedAT0_body(const float* __restrict__ Am, u32* __restrict__ Fm,
                              float* __restrict__ vec, int mat, int chunk,
                              float* __restrict__ Pm, float* wsh, float* shA) {
    constexpr int RPW = R / 4;
    constexpr int NU4 = N >> 4;       // 16-elem groups per row
    constexpr int KK  = N >> 11;
    const int tid = threadIdx.x, wv = tid >> 6, lane = tid & 63;
    const int row0 = chunk * R;

    // ---- phase 1: convert + row dots ----
    float inv = rsqrtf(vec[B28OFF + mat * (K_STEPS + 1)]);
    const float4* vp = (const float4*)(vec + UOFF + mat * VCAP);
    float aacc = 0.0f;
#pragma unroll
    for (int rr = 0; rr < RPW; ++rr) {
        int rl = wv * RPW + rr;
        int row = row0 + rl;
        const float4* Ar = (const float4*)(Am + (size_t)row * N);
        uint4* Fr = (uint4*)((char*)Fm + (size_t)row * N);
        float s = 0.0f;
#pragma unroll
        for (int c = lane; c < NU4; c += 64) {
            float4 a0 = Ar[4 * c + 0], a1 = Ar[4 * c + 1];
            float4 a2 = Ar[4 * c + 2], a3 = Ar[4 * c + 3];
            uint4 o;
            o.x = __builtin_amdgcn_cvt_pk_fp8_f32(a0.x, a0.y, 0u, false);
            o.x = __builtin_amdgcn_cvt_pk_fp8_f32(a0.z, a0.w, o.x, true);
            o.y = __builtin_amdgcn_cvt_pk_fp8_f32(a1.x, a1.y, 0u, false);
            o.y = __builtin_amdgcn_cvt_pk_fp8_f32(a1.z, a1.w, o.y, true);
            o.z = __builtin_amdgcn_cvt_pk_fp8_f32(a2.x, a2.y, 0u, false);
            o.z = __builtin_amdgcn_cvt_pk_fp8_f32(a2.z, a2.w, o.z, true);
            o.w = __builtin_amdgcn_cvt_pk_fp8_f32(a3.x, a3.y, 0u, false);
            o.w = __builtin_amdgcn_cvt_pk_fp8_f32(a3.z, a3.w, o.w, true);
            Fr[c] = o;
            float4 u0 = vp[4 * c + 0], u1 = vp[4 * c + 1];
            float4 u2 = vp[4 * c + 2], u3 = vp[4 * c + 3];
            f32x2 f0 = up8(o.x, false), f1 = up8(o.x, true);
            f32x2 f2 = up8(o.y, false), f3 = up8(o.y, true);
            f32x2 f4 = up8(o.z, false), f5 = up8(o.z, true);
            f32x2 f6 = up8(o.w, false), f7 = up8(o.w, true);
            s += f0[0] * u0.x + f0[1] * u0.y + f1[0] * u0.z + f1[1] * u0.w
               + f2[0] * u1.x + f2[1] * u1.y + f3[0] * u1.z + f3[1] * u1.w
               + f4[0] * u2.x + f4[1] * u2.y + f5[0] * u2.z + f5[1] * u2.w
               + f6[0] * u3.x + f6[1] * u3.y + f7[0] * u3.z + f7[1] * u3.w;
        }
#pragma unroll
        for (int off = 32; off; off >>= 1) s += __shfl_down(s, off, 64);
        if (lane == 0) { wsh[rl] = s * inv; aacc += s * s; }
    }
    if (lane == 0) shA[wv] = aacc;
    __syncthreads();
    if (tid == 0)
        atomicAdd(&vec[AL8OFF + mat * K_STEPS],
                  (shA[0] + shA[1] + shA[2] + shA[3]) * inv * inv);

    // ---- phase 2: column partials from F (just written; same-XCD L2 or HBM) ----
#pragma unroll
    for (int kk = 0; kk < KK; ++kk) {
        int col = (tid + (kk << 8)) << 3;
        const char* bb = (const char*)Fm + (size_t)row0 * N + col;
        float a0 = 0, a1 = 0, a2 = 0, a3 = 0, a4 = 0, a5 = 0, a6 = 0, a7 = 0;
#pragma unroll 8
        for (int r = 0; r < R; ++r) {
            uint2 a = *(const uint2*)(bb + (size_t)r * N);
            f32x2 f0 = up8(a.x, false), f1 = up8(a.x, true);
            f32x2 f2 = up8(a.y, false), f3 = up8(a.y, true);
            float w = wsh[r];
            a0 += f0[0] * w; a1 += f0[1] * w; a2 += f1[0] * w; a3 += f1[1] * w;
            a4 += f2[0] * w; a5 += f2[1] * w; a6 += f3[0] * w; a7 += f3[1] * w;
        }
        float* Pp = Pm + (size_t)chunk * N + col;
        float4 lo = {a0, a1, a2, a3}, hi = {a4, a5, a6, a7};
        ((float4*)Pp)[0] = lo;
        ((float4*)Pp)[1] = hi;
    }
}

__global__ __launch_bounds__(256) void k_fusedAT0(const float* __restrict__ A0,
                                                  const float* __restrict__ A1,
                                                  const float* __restrict__ A2,
                                                  u32* __restrict__ F,
                                                  float* __restrict__ vec) {
    __shared__ float wsh[32];
    __shared__ float shA[4];
    int bid = blockIdx.x;
    if (bid < 256) {
        fusedAT0_body<4096, 16>(A0, (u32*)((char*)F + (size_t)0 * MELEMS),
                                vec, 0, bid, vec + P8OFF + pbase(0), wsh, shA);
    } else if (bid < 512) {
        fusedAT0_body<2048, 32>(A1, (u32*)((char*)F + (size_t)1 * MELEMS),
                                vec, 1, bid - 256, vec + P8OFF + pbase(1), wsh, shA);
    } else {
        fusedAT0_body<8192, 8>(A2, (u32*)((char*)F + (size_t)2 * MELEMS),
                               vec, 2, bid - 512, vec + P8OFF + pbase(2), wsh, shA);
    }
}

// ---- steps 1..K-1: R8-proven fused step kernel (64 KB tile) ----
template <int N, int R>
__device__ void fusedAT_body(const u32* __restrict__ Fm, float* __restrict__ vec,
                             int mat, int chunk, int j,
                             float* __restrict__ Pm, float* wsh, float* shA) {
    constexpr int RPW = R / 4;
    constexpr int NU4 = N >> 4;
    constexpr int KK  = N >> 11;
    const int tid = threadIdx.x, wv = tid >> 6, lane = tid & 63;
    const int row0 = chunk * R;

    // ---- phase 1: row dots ----
    float inv = rsqrtf(vec[B28OFF + mat * (K_STEPS + 1) + j]);
    const float4* vp = (const float4*)(vec + UOFF + mat * VCAP);
    float aacc = 0.0f;
#pragma unroll
    for (int rr = 0; rr < RPW; ++rr) {
        int rl = wv * RPW + rr;
        const uint4* rp = (const uint4*)((const char*)Fm + (size_t)(row0 + rl) * N);
        float s = 0.0f;
#pragma unroll
        for (int c = lane; c < NU4; c += 64) {
            uint4 a = rp[c];
            float4 u0 = vp[4 * c + 0], u1 = vp[4 * c + 1];
            float4 u2 = vp[4 * c + 2], u3 = vp[4 * c + 3];
            f32x2 f0 = up8(a.x, false), f1 = up8(a.x, true);
            f32x2 f2 = up8(a.y, false), f3 = up8(a.y, true);
            f32x2 f4 = up8(a.z, false), f5 = up8(a.z, true);
            f32x2 f6 = up8(a.w, false), f7 = up8(a.w, true);
            s += f0[0] * u0.x + f0[1] * u0.y + f1[0] * u0.z + f1[1] * u0.w
               + f2[0] * u1.x + f2[1] * u1.y + f3[0] * u1.z + f3[1] * u1.w
               + f4[0] * u2.x + f4[1] * u2.y + f5[0] * u2.z + f5[1] * u2.w
               + f6[0] * u3.x + f6[1] * u3.y + f7[0] * u3.z + f7[1] * u3.w;
        }
#pragma unroll
        for (int off = 32; off; off >>= 1) s += __shfl_down(s, off, 64);
        if (lane == 0) { wsh[rl] = s * inv; aacc += s * s; }
    }
    if (lane == 0) shA[wv] = aacc;
    __syncthreads();
    if (tid == 0)
        atomicAdd(&vec[AL8OFF + mat * K_STEPS + j],
                  (shA[0] + shA[1] + shA[2] + shA[3]) * inv * inv);

    // ---- phase 2: column partials (tile L2-hot) ----
#pragma unroll
    for (int kk = 0; kk < KK; ++kk) {
        int col = (tid + (kk << 8)) << 3;
        const char* bb = (const char*)Fm + (size_t)row0 * N + col;
        float a0 = 0, a1 = 0, a2 = 0, a3 = 0, a4 = 0, a5 = 0, a6 = 0, a7 = 0;
#pragma unroll 8
        for (int r = 0; r < R; ++r) {
            uint2 a = *(const uint2*)(bb + (size_t)r * N);
            f32x2 f0 = up8(a.x, false), f1 = up8(a.x, true);
            f32x2 f2 = up8(a.y, false), f3 = up8(a.y, true);
            float w = wsh[r];
            a0 += f0[0] * w; a1 += f0[1] * w; a2 += f1[0] * w; a3 += f1[1] * w;
            a4 += f2[0] * w; a5 += f2[1] * w; a6 += f3[0] * w; a7 += f3[1] * w;
        }
        float* Pp = Pm + (size_t)chunk * N + col;
        float4 lo = {a0, a1, a2, a3}, hi = {a4, a5, a6, a7};
        ((float4*)Pp)[0] = lo;
        ((float4*)Pp)[1] = hi;
    }
}

__global__ __launch_bounds__(256) void k_fusedAT(const u32* __restrict__ F,
                                                 float* __restrict__ vec, int j) {
    __shared__ float wsh[32];
    __shared__ float shA[4];
    int bid = blockIdx.x;
    if (bid < 256) {
        fusedAT_body<4096, 16>((const u32*)((const char*)F + (size_t)0 * MELEMS),
                               vec, 0, bid, j, vec + P8OFF + pbase(0), wsh, shA);
    } else if (bid < 512) {
        fusedAT_body<2048, 32>((const u32*)((const char*)F + (size_t)1 * MELEMS),
                               vec, 1, bid - 256, j, vec + P8OFF + pbase(1), wsh, shA);
    } else {
        fusedAT_body<8192, 8>((const u32*)((const char*)F + (size_t)2 * MELEMS),
                              vec, 2, bid - 512, j, vec + P8OFF + pbase(2), wsh, shA);
    }
}

// reduce 256 partials/column; r = z - alpha v - beta_prev v0; basis write; beta^2.
__global__ __launch_bounds__(256) void k_stepR8(float* __restrict__ vec, int j) {
    int bid = blockIdx.x, tid = threadIdx.x;
    int mat, col0, n;
    if (bid < 16)      { mat = 0; n = 4096; col0 = bid << 8; }
    else if (bid < 24) { mat = 1; n = 2048; col0 = (bid - 16) << 8; }
    else               { mat = 2; n = 8192; col0 = (bid - 24) << 8; }
    int col = col0 + tid;
    const float* P = vec + P8OFF + pbase(mat);
    float z = 0.0f;
#pragma unroll 8
    for (int rc = 0; rc < NCHUNK; ++rc) z += P[(size_t)rc * n + col];
    float b2p = vec[B28OFF + mat * (K_STEPS + 1) + j];
    float bp = sqrtf(b2p);
    float inv = 1.0f / bp;
    float alpha = vec[AL8OFF + mat * K_STEPS + j];
    int g = mat * VCAP + col;
    float v1 = vec[UOFF + g] * inv;
    float r = z - alpha * v1 - bp * vec[V0OFF + g];
    vec[V0OFF + g] = v1;
    vec[UOFF + g] = r;
    vec[BASOFF + (mat * K_STEPS + j) * VCAP + col] = v1;
    float rr2 = blockReduce(r * r);
    if (tid == 0) atomicAdd(&vec[B28OFF + mat * (K_STEPS + 1) + j + 1], rr2);
}

// Sturm lambda_max + 3 inverse iterations -> y ; v* = Basis^T y (quarter per block).
__global__ __launch_bounds__(256) void k_final3(float* __restrict__ vec) {
    int bid = blockIdx.x;
    int mat = bid >> 2, q = bid & 3, tid = threadIdx.x, lane = tid & 63, wv = tid >> 6;
    int n = matN(mat);
    __shared__ double sa[K_STEPS], sb[K_STEPS];
    __shared__ double lamS;
    __shared__ float yl[K_STEPS];
    if (tid < K_STEPS) {
        sa[tid] = (double)vec[AL8OFF + mat * K_STEPS + tid];
        sb[tid] = (tid < K_STEPS - 1)
            ? sqrt((double)vec[B28OFF + mat * (K_STEPS + 1) + tid + 1]) : 0.0;
    }
    __syncthreads();
    if (wv == 0) {
        double g = 0.0;
        if (lane < K_STEPS) {
            double bl = lane ? sb[lane - 1] : 0.0;
            g = sa[lane] + bl + sb[lane];
        }
#pragma unroll
        for (int off = 32; off; off >>= 1) {
            double o = __shfl_xor(g, off, 64);
            if (o > g) g = o;
        }
        double lo = 0.0, hi = g > 0.0 ? g : 1.0;
        for (int round = 0; round < 4; ++round) {
            double step = (hi - lo) / 65.0;
            double x = lo + step * (double)(lane + 1);
            int cnt = 0;
            double d = 1.0;
            for (int i = 0; i < K_STEPS; ++i) {
                double off2 = 0.0;
                if (i) { double b = sb[i - 1]; off2 = b * b / d; }
                d = (sa[i] - x) - off2;
                if (d == 0.0) d = -1e-300;
                if (d < 0.0) cnt++;
            }
            unsigned long long mask = __ballot(cnt >= K_STEPS);
            if (mask) {
                int idx = __ffsll(mask) - 1;
                hi = lo + step * (double)(idx + 1);
                lo = lo + step * (double)idx;
            } else {
                lo = lo + step * 64.0;
            }
        }
        if (lane == 0) lamS = 0.5 * (lo + hi);
    }
    __syncthreads();
    if (tid == 0) {
        double lam2 = lamS * (1.0 + 1e-7);
        double x[K_STEPS], cp[K_STEPS];
        for (int i = 0; i < K_STEPS; ++i) x[i] = 1.0;
        for (int it = 0; it < 3; ++it) {
            double d = sa[0] - lam2;
            if (fabs(d) < 1e-14) d = (d < 0.0 ? -1e-14 : 1e-14);
            cp[0] = sb[0] / d;
            x[0] = x[0] / d;
            for (int i = 1; i < K_STEPS; ++i) {
                double m = (sa[i] - lam2) - sb[i - 1] * cp[i - 1];
                if (fabs(m) < 1e-14) m = (m < 0.0 ? -1e-14 : 1e-14);
                if (i < K_STEPS - 1) cp[i] = sb[i] / m;
                x[i] = (x[i] - sb[i - 1] * x[i - 1]) / m;
            }
            for (int i = K_STEPS - 2; i >= 0; --i) x[i] -= cp[i] * x[i + 1];
            double nr = 0.0;
            for (int i = 0; i < K_STEPS; ++i) nr += x[i] * x[i];
            nr = 1.0 / sqrt(nr);
            for (int i = 0; i < K_STEPS; ++i) x[i] *= nr;
        }
        for (int i = 0; i < K_STEPS; ++i) yl[i] = (float)x[i];
    }
    __syncthreads();
    int qn = n >> 2;
    int c0 = q * qn, c1 = c0 + qn;
    const float* BAS = vec + BASOFF + mat * K_STEPS * VCAP;
    float ns = 0.0f;
    for (int c = c0 + tid; c < c1; c += 256) {
        float acc = 0.0f;
#pragma unroll
        for (int jj = 0; jj < K_STEPS; ++jj) acc += yl[jj] * BAS[jj * VCAP + c];
        vec[WOFF + mat * VCAP + c] = acc;
        ns += acc * acc;
    }
    float t = blockReduce(ns);
    if (tid == 0) atomicAdd(&vec[NS2OFF + mat], t);
}

// ||A v*||^2 on ORIGINAL fp32 matrices. 896 blocks x 1024 thr, wave-per-row.
__global__ __launch_bounds__(1024) void k_rq(const float* __restrict__ A0,
                                             const float* __restrict__ A1,
                                             const float* __restrict__ A2,
                                             float* __restrict__ vec) {
    __shared__ float shA[16];
    int bid = blockIdx.x, tid = threadIdx.x, wv = tid >> 6, lane = tid & 63;
    int mat, row0, n;
    if (bid < 256)      { mat = 0; n = 4096; row0 = bid << 4; }
    else if (bid < 768) { mat = 1; n = 2048; row0 = (bid - 256) << 4; }
    else                { mat = 2; n = 8192; row0 = (bid - 768) << 4; }
    const float* A = mat == 0 ? A0 : (mat == 1 ? A1 : A2);
    int row = row0 + wv;
    const float4* rp = (const float4*)(A + (size_t)row * n);
    const float4* vp = (const float4*)(vec + WOFF + mat * VCAP);
    int nf4 = n >> 2;
    float s = 0.0f;
    for (int c = lane; c < nf4; c += 64) {
        float4 a = rp[c], v = vp[c];
        s += a.x * v.x + a.y * v.y + a.z * v.z + a.w * v.w;
    }
#pragma unroll
    for (int off = 32; off; off >>= 1) s += __shfl_down(s, off, 64);
    if (lane == 0) shA[wv] = s * s;
    __syncthreads();
    if (tid == 0) {
        float t = 0.0f;
#pragma unroll
        for (int k = 0; k < 16; ++k) t += shA[k];
        atomicAdd(&vec[RQ2OFF + mat], t);
    }
}

__global__ void k_out(const float* __restrict__ vec, float* __restrict__ out) {
    if (threadIdx.x == 0 && blockIdx.x == 0) {
        float s = 0.0f;
        for (int m = 0; m < 3; ++m)
            s += sqrtf(vec[RQ2OFF + m] / vec[NS2OFF + m]);
        out[0] = 1e-4f * s;
    }
}

// ======================= fp32 last-resort fallback =======================
__global__ __launch_bounds__(1024) void k_init(float* vec) {
    int mat = blockIdx.x;
    int n = matN(mat);
    float* V0 = vec + mat * VCAP;
    float* V1 = vec + 3 * VCAP + mat * VCAP;
    float* Z  = vec + 9 * VCAP + mat * VCAP;
    int tid = threadIdx.x;
    float acc = 0.0f;
    for (int i = tid; i < VCAP; i += 1024) {
        float val = 0.0f;
        if (i < n) {
            unsigned h = (unsigned)(i * 2654435761u) ^ (0x9E3779B9u * (unsigned)(mat + 1));
            h ^= h >> 16; h *= 0x85EBCA6Bu; h ^= h >> 13; h *= 0xC2B2AE35u; h ^= h >> 16;
            val = ((h >> 8) * (1.0f / 16777216.0f)) - 0.5f;
            acc += val * val;
        }
        V1[i] = val; V0[i] = 0.0f; Z[i] = 0.0f;
    }
    float nrm2 = blockReduce(acc);
    float inv = rsqrtf(nrm2);
    for (int i = tid; i < n; i += 1024) V1[i] *= inv;
}

__global__ __launch_bounds__(256) void k_gemvA(const float* __restrict__ A0,
                                               const float* __restrict__ A1,
                                               const float* __restrict__ A2,
                                               float* __restrict__ vec) {
    const float* V1 = vec + 3 * VCAP;
    float* W = vec + 6 * VCAP;
    int wid = (int)((blockIdx.x * blockDim.x + threadIdx.x) >> 6);
    int lane = threadIdx.x & 63;
    int mat, row;
    if (wid < 4096)       { mat = 0; row = wid; }
    else if (wid < 12288) { mat = 1; row = wid - 4096; }
    else                  { mat = 2; row = wid - 12288; }
    const float* A = mat == 0 ? A0 : (mat == 1 ? A1 : A2);
    int n = matN(mat);
    const float4* rowp = (const float4*)(A + (size_t)row * n);
    const float4* vp = (const float4*)(V1 + mat * VCAP);
    int nf4 = n >> 2;
    float s = 0.0f;
    for (int t = lane; t < nf4; t += 64) {
        float4 a = rowp[t], v = vp[t];
        s += a.x * v.x + a.y * v.y + a.z * v.z + a.w * v.w;
    }
#pragma unroll
    for (int off = 32; off; off >>= 1) s += __shfl_down(s, off, 64);
    if (lane == 0) W[mat * VCAP + row] = s;
}

__global__ __launch_bounds__(256) void k_gemvT(const float* __restrict__ A0,
                                               const float* __restrict__ A1,
                                               const float* __restrict__ A2,
                                               float* __restrict__ vec) {
    const float* W = vec + 6 * VCAP;
    float* Z = vec + 9 * VCAP;
    int bid = blockIdx.x;
    int mat = bid >> 8;
    int t = bid & 255;
    int n = matN(mat);
    int nColTiles = n >> 10;
    int colTile = t % nColTiles;
    int rowChunk = t / nColTiles;
    int r0 = rowChunk * 64;
    int col = colTile * 1024 + threadIdx.x * 4;
    const float* A = mat == 0 ? A0 : (mat == 1 ? A1 : A2);
    __shared__ float wsh[64];
    if (threadIdx.x < 64) wsh[threadIdx.x] = W[mat * VCAP + r0 + threadIdx.x];
    __syncthreads();
    const float* Ab = A + (size_t)r0 * n + col;
    float4 s = {0.0f, 0.0f, 0.0f, 0.0f};
#pragma unroll 4
    for (int r = 0; r < 64; ++r) {
        float4 a = *(const float4*)(Ab + (size_t)r * n);
        float w = wsh[r];
        s.x += a.x * w; s.y += a.y * w; s.z += a.z * w; s.w += a.w * w;
    }
    float* Zm = Z + mat * VCAP + col;
    atomicAdd(Zm + 0, s.x);
    atomicAdd(Zm + 1, s.y);
    atomicAdd(Zm + 2, s.z);
    atomicAdd(Zm + 3, s.w);
}

__global__ __launch_bounds__(1024) void k_update(float* __restrict__ vec, int j) {
    int mat = blockIdx.x;
    int n = matN(mat);
    float* V0 = vec + mat * VCAP;
    float* V1 = vec + 3 * VCAP + mat * VCAP;
    float* Z  = vec + 9 * VCAP + mat * VCAP;
    float* ALPHA = vec + FB_AOFF;
    float* BETA  = ALPHA + 3 * K_STEPS;
    int tid = threadIdx.x;
    float acc = 0.0f;
    for (int i = tid; i < n; i += 1024) acc += V1[i] * Z[i];
    float alpha = blockReduce(acc);
    float bp = (j > 0) ? BETA[mat * K_STEPS + j - 1] : 0.0f;
    float acc2 = 0.0f;
    for (int i = tid; i < n; i += 1024) {
        float v1 = V1[i];
        float r = Z[i] - alpha * v1 - bp * V0[i];
        V0[i] = v1;
        Z[i] = r;
        acc2 += r * r;
    }
    float b2 = blockReduce(acc2);
    float beta = sqrtf(b2);
    float inv = (beta > 1e-20f) ? (1.0f / beta) : 0.0f;
    for (int i = tid; i < n; i += 1024) {
        V1[i] = Z[i] * inv;
        Z[i] = 0.0f;
    }
    if (tid == 0) {
        ALPHA[mat * K_STEPS + j] = alpha;
        BETA[mat * K_STEPS + j] = beta;
    }
}

__global__ __launch_bounds__(256) void k_final2(const float* __restrict__ vec,
                                                float* __restrict__ out) {
    __shared__ double sa[3][K_STEPS], sb[3][K_STEPS];
    __shared__ double sig[3];
    int tid = threadIdx.x, wid = tid >> 6, lane = tid & 63;
    if (wid < 3 && lane < K_STEPS) {
        const float* AL = vec + FB_AOFF + wid * K_STEPS;
        const float* BE = vec + FB_AOFF + 3 * K_STEPS + wid * K_STEPS;
        sa[wid][lane] = (double)AL[lane];
        sb[wid][lane] = (lane < K_STEPS - 1) ? (double)BE[lane] : 0.0;
    }
    __syncthreads();
    if (wid < 3) {
        double g = 0.0;
        if (lane < K_STEPS) {
            double bl_ = lane ? sb[wid][lane - 1] : 0.0;
            g = sa[wid][lane] + bl_ + sb[wid][lane];
        }
#pragma unroll
        for (int off = 32; off; off >>= 1) {
            double o = __shfl_xor(g, off, 64);
            if (o > g) g = o;
        }
        double lo = 0.0, hi = g > 0.0 ? g : 1.0;
        for (int round = 0; round < 4; ++round) {
            double step = (hi - lo) / 65.0;
            double x = lo + step * (double)(lane + 1);
            int cnt = 0;
            double d = 1.0;
            for (int i = 0; i < K_STEPS; ++i) {
                double off2 = 0.0;
                if (i) { double b = sb[wid][i - 1]; off2 = b * b / d; }
                d = (sa[wid][i] - x) - off2;
                if (d == 0.0) d = -1e-300;
                if (d < 0.0) cnt++;
            }
            unsigned long long mask = __ballot(cnt >= K_STEPS);
            if (mask) {
                int idx = __ffsll(mask) - 1;
                hi = lo + step * (double)(idx + 1);
                lo = lo + step * (double)idx;
            } else {
                lo = lo + step * 64.0;
            }
        }
        if (lane == 0) {
            double lam = 0.5 * (lo + hi);
            sig[wid] = sqrt(lam > 0.0 ? lam : 0.0);
        }
    }
    __syncthreads();
    if (tid == 0) out[0] = (float)(1e-4 * (sig[0] + sig[1] + sig[2]));
}

extern "C" void kernel_launch(void* const* d_in, const int* in_sizes, int n_in,
                              void* d_out, int out_size, void* d_ws, size_t ws_size,
                              hipStream_t stream) {
    const float* A0 = (const float*)d_in[0];
    const float* A1 = (const float*)d_in[1];
    const float* A2 = (const float*)d_in[2];
    float* out = (float*)d_out;

    const size_t f8_bytes = (size_t)3 * MELEMS;
    const size_t vec8_bytes = (size_t)VEC8_FLOATS * 4 + 1024;

    if (ws_size >= f8_bytes + vec8_bytes) {
        u32* F = (u32*)d_ws;
        float* vec = (float*)((char*)d_ws + f8_bytes);
        hipLaunchKernelGGL(k_init8, dim3(4), dim3(256), 0, stream, vec);
        hipLaunchKernelGGL(k_fusedAT0, dim3(768), dim3(256), 0, stream, A0, A1, A2, F, vec);
        hipLaunchKernelGGL(k_stepR8, dim3(56), dim3(256), 0, stream, vec, 0);
        for (int j = 1; j < K_STEPS; ++j) {
            hipLaunchKernelGGL(k_fusedAT, dim3(768), dim3(256), 0, stream, F, vec, j);
            hipLaunchKernelGGL(k_stepR8, dim3(56), dim3(256), 0, stream, vec, j);
        }
        hipLaunchKernelGGL(k_final3, dim3(12), dim3(256), 0, stream, vec);
        hipLaunchKernelGGL(k_rq, dim3(896), dim3(1024), 0, stream, A0, A1, A2, vec);
        hipLaunchKernelGGL(k_out, dim3(1), dim3(64), 0, stream, vec, out);
    } else {
        float* vec = (float*)d_ws;
        hipLaunchKernelGGL(k_init, dim3(3), dim3(1024), 0, stream, vec);
        for (int j = 0; j < K_STEPS; ++j) {
            hipLaunchKernelGGL(k_gemvA, dim3(3584), dim3(256), 0, stream, A0, A1, A2, vec);
            hipLaunchKernelGGL(k_gemvT, dim3(768), dim3(256), 0, stream, A0, A1, A2, vec);
            hipLaunchKernelGGL(k_update, dim3(3), dim3(1024), 0, stream, vec, j);
        }
        hipLaunchKernelGGL(k_final2, dim3(1), dim3(256), 0, stream, vec, out);
    }
}